// Round 3
// baseline (7357.935 us; speedup 1.0000x reference)
//
#include <hip/hip_runtime.h>
#include <math.h>
#include <utility>

#define TB 1024   // batch
#define HH 100    // hidden
#define GG 300    // 3*H gate rows

// ---------------------------------------------------------------------------
// NUMERICS ARE FROZEN — DO NOT TOUCH.
// R1 (__expf), R5 (naive exp2), R6 (1-ulp Cody-Waite expm1) ALL flipped the
// same decoder argmax site (absmax=14). Only the ocml expf/tanhf profile
// lands on the reference side of a knife-edge logit near-tie. The
// transcendentals AND the per-element GEMV/gate expression DAG (values,
// pairing, order) must stay bit-identical. gemv4 and gemv_lds are proven
// bit-equivalent per-group (R10 used gemv_lds, R11 used gemv4, both passed).
//
// R13: REGISTER-ALLOCATOR RULE (3 data points, R10/R11/R12):
//   arch-VGPR cap = 512 / (2 x declared min_waves_per_EU)
//   (launch_bounds(.,3)->84, (.,2)->128, waves_per_eu(3,3)->84)
// Overflow is spilled to AGPRs: invisible in VGPR_Count, no scratch, but on
// gfx950's UNIFIED file it still eats the occupancy budget (~240/wave -> 2
// waves/SIMD -> 8 waves/CU -> R12's grid-512 ran as TWO sequential passes,
// occupancy 14.8% = 5/32) AND every in-loop pin pays accvgpr copies.
// Fix: launch_bounds(320, 1) -> cap 256: weights fit in ARCH regs, no AGPR.
// Residency: BT=4, grid 256 = 1 block/CU, full batch in ONE pass. A 5-wave
// block is schedulable at any alloc <= 256 (2x256=512/SIMD) — no cliff.
// ---------------------------------------------------------------------------
__device__ __forceinline__ float sigmoidf_(float x) {
    return 1.0f / (1.0f + expf(-x));
}
__device__ __forceinline__ float tanhf_(float x) {
    return tanhf(x);
}

template<size_t... Is>
__device__ __forceinline__ void ldN(std::index_sequence<Is...>,
                                    float* __restrict__ dst,
                                    const float* __restrict__ src) {
    ((dst[Is] = src[Is]), ...);
}
__device__ __forceinline__ float pin_val(float v) {
    asm volatile("" : "+v"(v));
    return v;
}
// IN-LOOP PIN (R10): non-rematerializable SSA chain -> weights stay resident.
// Zero instructions when the home is an arch VGPR (ensured by cap=256).
template<size_t... Is>
__device__ __forceinline__ void pinN(std::index_sequence<Is...>, float* w) {
    ((w[Is] = pin_val(w[Is])), ...);
}

// acc += w-row (registers) dot vec (LDS broadcast), float4-grouped.
// EXACT expression shape shared by acc_i and acc_h paths (frozen DAG).
template<int KK, int BT, int LD>
__device__ __forceinline__ void fma_step(const float* __restrict__ w,
                                         const float (*xs)[LD],
                                         float* __restrict__ acc) {
    #pragma unroll
    for (int b = 0; b < BT; ++b) {
        const float4 xv = *reinterpret_cast<const float4*>(&xs[b][KK]);
        acc[b] += w[KK]     * xv.x + w[KK + 1] * xv.y
                + w[KK + 2] * xv.z + w[KK + 3] * xv.w;
    }
}
template<int BT, int LD, size_t... Is>
__device__ __forceinline__ void gemv4(std::index_sequence<Is...>,
                                      const float* __restrict__ w,
                                      const float (*xs)[LD],
                                      float* __restrict__ acc) {
    (fma_step<(int)(Is * 4), BT, LD>(w, xs, acc), ...);
}

// acc_h variant: weights from LDS k-packed [grp][row][4], h broadcast from LDS.
// Pairing/order identical to fma_step: wv.x==w[4g+0] pairs hv.x==h[4g+0], ...
template<int GRP, int BT>
__device__ __forceinline__ void fma_lds_step(const float* __restrict__ wl,
                                             int row,
                                             const float (*hs)[HH],
                                             float* __restrict__ acc) {
    const float4 wv = *reinterpret_cast<const float4*>(wl + (GRP * GG + row) * 4);
    #pragma unroll
    for (int b = 0; b < BT; ++b) {
        const float4 hv = *reinterpret_cast<const float4*>(&hs[b][GRP * 4]);
        acc[b] += wv.x * hv.x + wv.y * hv.y + wv.z * hv.z + wv.w * hv.w;
    }
}
template<int BT, size_t... Is>
__device__ __forceinline__ void gemv_lds(std::index_sequence<Is...>,
                                         const float* __restrict__ wl, int row,
                                         const float (*hs)[HH],
                                         float* __restrict__ acc) {
    (fma_lds_step<(int)Is, BT>(wl, row, hs, acc), ...);
}

// ===========================================================================
// Small-K GRU (K=26): 320 thr, BT=4, grid 256 (1 block/CU, batch resident in
// one pass). BOTH wih[28] and whh[100] rows in arch VGPRs (~190 <= cap 256).
// LDS carries only broadcasts (x/h/r/z) — zero lane-varying reads in loop.
// ===========================================================================
template<int K, bool EMB, bool WRITE_SEQ>
__global__ __launch_bounds__(320, 1)
void gru_small(const float* __restrict__ xin,   // [T,B,K] (if !EMB)
               const int*   __restrict__ tgt,   // [T,B]   (if EMB)
               const float* __restrict__ emb,   // [64,26] (if EMB)
               const float* __restrict__ Wih,   // [300,K]
               const float* __restrict__ Whh,   // [300,100]
               const float* __restrict__ bih,
               const float* __restrict__ bhh,
               const float* __restrict__ h_init,// [B,100] or null -> zeros
               float* __restrict__ seq_out,     // [T,B,100] (if WRITE_SEQ)
               float* __restrict__ h_last,      // [B,100] or null
               int T)
{
    constexpr int KP = (K + 3) & ~3;   // 28
    constexpr int BT = 4;              // batch per block
    static_assert(KP % 4 == 0, "");
    static_assert(BT * K <= 320, "");

    const int tj  = threadIdx.x;       // row index (0..319)
    const int bb0 = blockIdx.x * BT;
    const int g   = tj / 100;
    const int i   = tj % 100;

    __shared__ __align__(16) float h_s[BT][HH];
    __shared__ __align__(16) float x_s[BT][KP];
    __shared__ float r_s[BT][HH];
    __shared__ float z_s[BT][HH];
    __shared__ float emb_s[EMB ? 64 : 1][EMB ? 28 : 4];
    __shared__ int   tgt_s[BT];

    // ---- wih + whh rows into registers (one-time, clamped row for pads) ----
    const int jj = (tj < GG) ? tj : 0;
    float wih[KP];
    ldN(std::make_index_sequence<K>{}, wih, Wih + (long)jj * K);
    #pragma unroll
    for (int k = K; k < KP; ++k) wih[k] = 0.f;
    float whr[HH];
    ldN(std::make_index_sequence<HH>{}, whr, Whh + (long)jj * HH);
    float bi = bih[jj];
    float bh = bhh[jj];

    // ---- init h ----
    for (int idx = tj; idx < BT * HH; idx += 320) {
        int b = idx / HH, k = idx % HH;
        h_s[b][k] = h_init ? h_init[(bb0 + b) * HH + k] : 0.f;
    }
    // ---- init x_s for t=0 ----
    if constexpr (EMB) {
        for (int idx = tj; idx < 64 * 28; idx += 320) {
            int d = idx / 28, k = idx % 28;
            emb_s[d][k] = (k < 26) ? emb[d * 26 + k] : 0.f;
        }
        __syncthreads();
        for (int idx = tj; idx < BT * KP; idx += 320) {
            int b = idx / KP, k = idx % KP;
            int t0 = tgt[bb0 + b];
            x_s[b][k] = emb_s[t0][k];    // pads are 0 via emb_s
        }
    } else {
        for (int idx = tj; idx < BT * KP; idx += 320) {
            int b = idx / KP, k = idx % KP;
            x_s[b][k] = (k < K) ? xin[(bb0 + b) * K + k] : 0.f;
        }
    }
    __syncthreads();   // h_s, x_s ready

    // ---- time loop ----
    for (int t = 0; t < T; ++t) {
        pinN(std::make_index_sequence<KP>{}, wih);
        pinN(std::make_index_sequence<HH>{}, whr);
        bi = pin_val(bi);
        bh = pin_val(bh);

        const bool has_next = (t + 1 < T);

        // prefetch next step's input into regs (hidden under FMA loop)
        float px0 = 0.f;
        int   ptg = 0;
        if constexpr (!EMB) {
            if (has_next && tj < BT * K)
                px0 = xin[((t + 1) * TB + bb0 + tj / K) * K + tj % K];
        } else {
            if (has_next && tj < BT) ptg = tgt[(t + 1) * TB + bb0 + tj];
        }

        // main GEMV: acc_i = Wih[j,:].x + bi ; acc_h = Whh[j,:].h + bh
        float acc_i[BT], acc_h[BT];
        #pragma unroll
        for (int b = 0; b < BT; ++b) { acc_i[b] = bi; acc_h[b] = bh; }

        gemv4<BT, KP>(std::make_index_sequence<KP / 4>{}, wih, x_s, acc_i);
        gemv4<BT, HH>(std::make_index_sequence<HH / 4>{}, whr, h_s, acc_h);

        // r / z gates -> LDS
        if (tj < 200) {
            #pragma unroll
            for (int b = 0; b < BT; ++b) {
                float v = sigmoidf_(acc_i[b] + acc_h[b]);
                if (g == 0) r_s[b][i] = v;
                else        z_s[b][i] = v;
            }
        }
        __syncthreads();   // B1: gates visible; h_s/x_s reads done

        if (tj >= 200 && tj < 300) {
            // n gate + state update (100 threads)
            #pragma unroll
            for (int b = 0; b < BT; ++b) {
                float n  = tanhf_(acc_i[b] + r_s[b][i] * acc_h[b]);
                float z  = z_s[b][i];
                float hn = (1.f - z) * n + z * h_s[b][i];
                h_s[b][i] = hn;
                if (WRITE_SEQ)
                    seq_out[((long)t * TB + bb0 + b) * HH + i] = hn;
            }
        }
        if constexpr (!EMB) {
            if (has_next && tj < BT * K) x_s[tj / K][tj % K] = px0;
        } else {
            if (has_next && tj < BT) tgt_s[tj] = ptg;
            __syncthreads();   // B2: tgt_s visible
            if (has_next && tj < BT * KP) {
                int b = tj / KP, k = tj % KP;
                x_s[b][k] = emb_s[tgt_s[b]][k];
            }
        }
        __syncthreads();       // step barrier: h_s and x_s ready
    }

    if (h_last != nullptr && tj >= 200 && tj < 300) {
        #pragma unroll
        for (int b = 0; b < BT; ++b)
            h_last[(bb0 + b) * HH + i] = h_s[b][i];
    }
}

// ===========================================================================
// Big-K GRU (K=100): 320 thr, BT=4, grid 256 (1 block/CU, batch resident in
// one pass — LDS 126.4KB forces 1 block/CU anyway). wih[100] in arch VGPRs
// (cap 256, no AGPR tax); whh k-packed in LDS (lane-varying b128, 2-way-free).
// ===========================================================================
template<int K, bool WRITE_SEQ>
__global__ __launch_bounds__(320, 1)
void gru_big(const float* __restrict__ xin,   // [T,B,K]
             const float* __restrict__ Wih,   // [300,K]
             const float* __restrict__ Whh,   // [300,100]
             const float* __restrict__ bih,
             const float* __restrict__ bhh,
             const float* __restrict__ h_init,// [B,100] or null -> zeros
             float* __restrict__ seq_out,     // [T,B,100] (if WRITE_SEQ)
             float* __restrict__ h_last,      // [B,100] or null
             int T)
{
    constexpr int KP = (K + 3) & ~3;   // 100
    constexpr int BT = 4;              // batch per block
    static_assert(KP % 4 == 0, "");

    const int tj  = threadIdx.x;       // row index (0..319)
    const int bb0 = blockIdx.x * BT;
    const int g   = tj / 100;
    const int i   = tj % 100;

    __shared__ __align__(16) float whh_l[(HH / 4) * GG * 4];  // 120000 B
    __shared__ __align__(16) float h_s[BT][HH];
    __shared__ __align__(16) float x_s[BT][KP];
    __shared__ float r_s[BT][HH];
    __shared__ float z_s[BT][HH];

    // ---- wih row into registers (one-time, clamped row for pads) ----
    const int jj = (tj < GG) ? tj : 0;
    float wih[KP];
    ldN(std::make_index_sequence<K>{}, wih, Wih + (long)jj * K);
    #pragma unroll
    for (int k = K; k < KP; ++k) wih[k] = 0.f;
    float bi = bih[jj];
    float bh = bhh[jj];

    // ---- stage whh into LDS, k-packed: whh_l[(k/4)*GG + row][k%4] ----
    for (int idx = tj; idx < GG * HH; idx += 320) {
        int row = idx / HH, k = idx % HH;
        whh_l[((k >> 2) * GG + row) * 4 + (k & 3)] = Whh[row * HH + k];
    }

    // ---- init h ----
    for (int idx = tj; idx < BT * HH; idx += 320) {
        int b = idx / HH, k = idx % HH;
        h_s[b][k] = h_init ? h_init[(bb0 + b) * HH + k] : 0.f;
    }
    // ---- init x_s for t=0 ----
    for (int idx = tj; idx < BT * KP; idx += 320) {
        int b = idx / KP, k = idx % KP;
        x_s[b][k] = (k < K) ? xin[(bb0 + b) * K + k] : 0.f;
    }
    __syncthreads();   // whh_l, h_s, x_s ready

    // ---- time loop ----
    for (int t = 0; t < T; ++t) {
        // IN-LOOP PIN: non-rematerializable SSA chain -> wih stays resident.
        pinN(std::make_index_sequence<KP>{}, wih);
        bi = pin_val(bi);
        bh = pin_val(bh);

        const bool has_next = (t + 1 < T);

        // prefetch next step's input into regs (hidden under FMA loop)
        float px0 = 0.f, px1 = 0.f;
        if (has_next) {
            // BT*K = 400 > 320: two strided chunks cover it
            px0 = xin[((t + 1) * TB + bb0 + tj / K) * K + tj % K];
            if (tj + 320 < BT * K)
                px1 = xin[((t + 1) * TB + bb0 + (tj + 320) / K) * K
                          + (tj + 320) % K];
        }

        // main GEMV: acc_i = Wih[j,:].x + bi ; acc_h = Whh[j,:].h + bh
        float acc_i[BT], acc_h[BT];
        #pragma unroll
        for (int b = 0; b < BT; ++b) { acc_i[b] = bi; acc_h[b] = bh; }

        gemv4<BT, KP>(std::make_index_sequence<KP / 4>{}, wih, x_s, acc_i);
        gemv_lds<BT>(std::make_index_sequence<HH / 4>{}, whh_l, jj, h_s, acc_h);

        // r / z gates -> LDS
        if (tj < 200) {
            #pragma unroll
            for (int b = 0; b < BT; ++b) {
                float v = sigmoidf_(acc_i[b] + acc_h[b]);
                if (g == 0) r_s[b][i] = v;
                else        z_s[b][i] = v;
            }
        }
        __syncthreads();   // B1: gates visible; h_s/x_s reads done

        if (tj >= 200 && tj < 300) {
            // n gate + state update (100 threads)
            #pragma unroll
            for (int b = 0; b < BT; ++b) {
                float n  = tanhf_(acc_i[b] + r_s[b][i] * acc_h[b]);
                float z  = z_s[b][i];
                float hn = (1.f - z) * n + z * h_s[b][i];
                h_s[b][i] = hn;
                if (WRITE_SEQ)
                    seq_out[((long)t * TB + bb0 + b) * HH + i] = hn;
            }
        }
        if (has_next) {
            x_s[tj / K][tj % K] = px0;
            if (tj + 320 < BT * K)
                x_s[(tj + 320) / K][(tj + 320) % K] = px1;
        }
        __syncthreads();       // step barrier: h_s and x_s ready
    }

    if (h_last != nullptr && tj >= 200 && tj < 300) {
        #pragma unroll
        for (int b = 0; b < BT; ++b)
            h_last[(bb0 + b) * HH + i] = h_s[b][i];
    }
}

// Final linear + argmax + target_cal.
// block = 256 = 4 slots x 64 lanes (lane = output class d, wave = one (p,b) slot)
__global__ __launch_bounds__(256)
void final_kernel(const float* __restrict__ d1,
                  const float* __restrict__ linW,   // [64,100]
                  const float* __restrict__ linb,   // [64]
                  const int*   __restrict__ tgt,    // [80,1024]
                  float* __restrict__ out0,         // [79*1024,64] logits
                  float* __restrict__ out1,         // [79*1024] target_cal
                  float* __restrict__ out2)         // [79*1024] argmax
{
    __shared__ float WT[HH][64];     // WT[k][d]
    __shared__ __align__(16) float row[4][HH];

    const int tid = threadIdx.x;
    for (int idx = tid; idx < 64 * HH; idx += 256) {
        int d = idx / HH, k = idx % HH;
        WT[k][d] = linW[idx];
    }
    const int s    = tid >> 6;
    const int d    = tid & 63;
    const int slot = blockIdx.x * 4 + s;     // < 79*1024
    const int p    = slot >> 10;
    const int b    = slot & 1023;
    const float* drow = &d1[(long)(p * TB + b) * HH];
    __syncthreads();
    if (d < 50) {
        float2 v = *reinterpret_cast<const float2*>(&drow[2 * d]);
        row[s][2 * d]     = v.x;
        row[s][2 * d + 1] = v.y;
    }
    __syncthreads();

    float acc = linb[d];
    #pragma unroll
    for (int k = 0; k < HH; ++k)
        acc += row[s][k] * WT[k][d];

    out0[(long)slot * 64 + d] = acc;

    // argmax over 64 lanes, first-occurrence tie-break (min index among maxima)
    float mv = acc;
    int   mi = d;
    #pragma unroll
    for (int off = 32; off >= 1; off >>= 1) {
        float ov = __shfl_xor(mv, off, 64);
        int   oi = __shfl_xor(mi, off, 64);
        if (ov > mv || (ov == mv && oi < mi)) { mv = ov; mi = oi; }
    }
    if (d == 0) out2[slot] = (float)mi;
    if (d == 1) out1[slot] = (float)tgt[(p + 1) * TB + b];
}

extern "C" void kernel_launch(void* const* d_in, const int* in_sizes, int n_in,
                              void* d_out, int out_size, void* d_ws, size_t ws_size,
                              hipStream_t stream)
{
    const float* x      = (const float*)d_in[0];
    const int*   target = (const int*)  d_in[1];
    const float* emb    = (const float*)d_in[2];
    const float* eWih0  = (const float*)d_in[3];
    const float* eWhh0  = (const float*)d_in[4];
    const float* ebih0  = (const float*)d_in[5];
    const float* ebhh0  = (const float*)d_in[6];
    const float* eWih1  = (const float*)d_in[7];
    const float* eWhh1  = (const float*)d_in[8];
    const float* ebih1  = (const float*)d_in[9];
    const float* ebhh1  = (const float*)d_in[10];
    const float* dWih0  = (const float*)d_in[11];
    const float* dWhh0  = (const float*)d_in[12];
    const float* dbih0  = (const float*)d_in[13];
    const float* dbhh0  = (const float*)d_in[14];
    const float* dWih1  = (const float*)d_in[15];
    const float* dWhh1  = (const float*)d_in[16];
    const float* dbih1  = (const float*)d_in[17];
    const float* dbhh1  = (const float*)d_in[18];
    const float* linW   = (const float*)d_in[19];
    const float* linb   = (const float*)d_in[20];

    // workspace layout (floats):
    //  [0, 102400)                       h_enc0
    //  [102400, 204800)                  h_enc1
    //  [204800, 204800+51.2M)            e0 during encoder
    //  same region reused for d0/d1 during decoder (e0 dead by then)
    float* ws     = (float*)d_ws;
    float* h_enc0 = ws;
    float* h_enc1 = ws + 102400;
    float* e0     = ws + 204800;                      // 500*1024*100
    float* d0     = ws + 204800;                      // aliases e0 (dead)
    float* d1_    = ws + 204800 + 80 * 1024 * 100;    // 80*1024*100

    // encoder layer 0: raw x input (K=26), write e0 + h_enc0
    gru_small<26, false, true ><<<dim3(256), dim3(320), 0, stream>>>(
        x, nullptr, nullptr, eWih0, eWhh0, ebih0, ebhh0, nullptr, e0, h_enc0, 500);
    // encoder layer 1: e0 input (K=100), only h_enc1 needed
    gru_big<100, false><<<dim3(256), dim3(320), 0, stream>>>(
        e0, eWih1, eWhh1, ebih1, ebhh1, nullptr, nullptr, h_enc1, 500);
    // decoder layer 0: embedding-gather input (K=26), h0 = h_enc0
    gru_small<26, true,  true ><<<dim3(256), dim3(320), 0, stream>>>(
        nullptr, target, emb, dWih0, dWhh0, dbih0, dbhh0, h_enc0, d0, nullptr, 80);
    // decoder layer 1: d0 input (K=100), h0 = h_enc1, write d1
    gru_big<100, true ><<<dim3(256), dim3(320), 0, stream>>>(
        d0, dWih1, dWhh1, dbih1, dbhh1, h_enc1, d1_, nullptr, 80);

    float* out0 = (float*)d_out;
    float* out1 = out0 + (long)79 * 1024 * 64;
    float* out2 = out1 + 79 * 1024;
    final_kernel<<<dim3(20224), dim3(256), 0, stream>>>(d1_, linW, linb, target,
                                                        out0, out1, out2);
}

// Round 4
// 3973.421 us; speedup vs baseline: 1.8518x; 1.8518x over previous
//
#include <hip/hip_runtime.h>
#include <math.h>
#include <utility>

#define TB 1024   // batch
#define HH 100    // hidden
#define GG 300    // 3*H gate rows

// ---------------------------------------------------------------------------
// NUMERICS ARE FROZEN — DO NOT TOUCH.
// Only the ocml expf/tanhf profile lands on the reference side of a
// knife-edge decoder argmax logit near-tie. The transcendentals AND the
// per-element GEMV/gate expression DAG (values, pairing, order) must stay
// bit-identical. gemv4 (reg weights) and gemv_lds (LDS weights) are proven
// bit-equivalent per-group (R10 vs R11 both passed); only operand SOURCE
// differs, chain order g0->g24 and in-group pairing are identical.
//
// R14 model (from R10-R13 counters):
//  * acc_i/wih path is ~free (enc0 K=26 == enc1 K=100 in R10 within 2.5%).
//  * Step time is LINEAR in BT with small intercept (~2150 cyc per
//    batch-element-step in EVERY config) => per-thread serial chain
//    (frozen left-assoc FMA chain + exposed LDS waits), hidden only by
//    OTHER resident waves. R13-big (1.25 waves/SIMD) exposed it fully.
//  * Allocator: explicit min-waves declarations cap arch-VGPR at
//    512/(2*min) (AGPR half-reservation on unified file). Pins on
//    AGPR-resident values force accvgpr copies; without pins AGPR
//    residency is ~free (VALU reads AGPR directly). R9==R10 proved
//    remat is perf-neutral. => ALL PINS REMOVED.
// R14 fix: TWO independent blocks per CU for the small kernel
// (independent barrier domains hide each other's chains), BT=1 per team:
// 640 thr = 2 teams x 320, grid 512, whh split 40k-in-regs / 60k-in-LDS
// (72KB => 2 blocks fit in 160KB), emb gathered from global (no emb_s).
// Big kernel: R10 structure, pins removed, launch_bounds(640) only.
// ---------------------------------------------------------------------------
__device__ __forceinline__ float sigmoidf_(float x) {
    return 1.0f / (1.0f + expf(-x));
}
__device__ __forceinline__ float tanhf_(float x) {
    return tanhf(x);
}

template<size_t... Is>
__device__ __forceinline__ void ldN(std::index_sequence<Is...>,
                                    float* __restrict__ dst,
                                    const float* __restrict__ src) {
    ((dst[Is] = src[Is]), ...);
}

// acc += w-row (registers) dot vec (LDS broadcast), float4-grouped.
// EXACT expression shape shared by all GEMV paths (frozen DAG).
template<int KK, int BT, int LD>
__device__ __forceinline__ void fma_step(const float* __restrict__ w,
                                         const float (*xs)[LD],
                                         float* __restrict__ acc) {
    #pragma unroll
    for (int b = 0; b < BT; ++b) {
        const float4 xv = *reinterpret_cast<const float4*>(&xs[b][KK]);
        acc[b] += w[KK]     * xv.x + w[KK + 1] * xv.y
                + w[KK + 2] * xv.z + w[KK + 3] * xv.w;
    }
}
template<int BT, int LD, size_t... Is>
__device__ __forceinline__ void gemv4(std::index_sequence<Is...>,
                                      const float* __restrict__ w,
                                      const float (*xs)[LD],
                                      float* __restrict__ acc) {
    (fma_step<(int)(Is * 4), BT, LD>(w, xs, acc), ...);
}

// weights from LDS k-packed [grp-OFF][row][4], h broadcast from LDS.
// Pairing/order identical to fma_step: wv.x==w[4g+0] pairs hv.x==h[4g+0].
template<int GRP, int OFF, int BT>
__device__ __forceinline__ void fma_lds_step(const float* __restrict__ wl,
                                             int row,
                                             const float (*hs)[HH],
                                             float* __restrict__ acc) {
    const float4 wv =
        *reinterpret_cast<const float4*>(wl + ((GRP - OFF) * GG + row) * 4);
    #pragma unroll
    for (int b = 0; b < BT; ++b) {
        const float4 hv = *reinterpret_cast<const float4*>(&hs[b][GRP * 4]);
        acc[b] += wv.x * hv.x + wv.y * hv.y + wv.z * hv.z + wv.w * hv.w;
    }
}
template<int OFF, int BT, size_t... Is>
__device__ __forceinline__ void gemv_lds(std::index_sequence<Is...>,
                                         const float* __restrict__ wl, int row,
                                         const float (*hs)[HH],
                                         float* __restrict__ acc) {
    (fma_lds_step<(int)Is + OFF, OFF, BT>(wl, row, hs, acc), ...);
}

// ===========================================================================
// Small-K GRU (K=26): 640 thr = 2 teams x 320, BT=1 per team, grid 512
// => target 2 blocks/CU (20 waves) with independent barrier domains.
// whh hybrid: k<40 in regs (whr[40]), k>=40 k-packed in LDS (72000 B).
// wih[28] in regs. Per-wave unified regs ~95-100 -> 5 waves/SIMD fits.
// ===========================================================================
template<bool EMB, bool WRITE_SEQ>
__global__ __launch_bounds__(640)
__attribute__((amdgpu_waves_per_eu(5, 5)))
void gru_small(const float* __restrict__ xin,   // [T,B,26] (if !EMB)
               const int*   __restrict__ tgt,   // [T,B]    (if EMB)
               const float* __restrict__ emb,   // [64,26]  (if EMB)
               const float* __restrict__ Wih,   // [300,26]
               const float* __restrict__ Whh,   // [300,100]
               const float* __restrict__ bih,
               const float* __restrict__ bhh,
               const float* __restrict__ h_init,// [B,100] or null -> zeros
               float* __restrict__ seq_out,     // [T,B,100] (if WRITE_SEQ)
               float* __restrict__ h_last,      // [B,100] or null
               int T)
{
    constexpr int K    = 26;
    constexpr int KP   = 28;
    constexpr int KREG = 40;   // whh k-values in registers
    constexpr int KLDS = HH - KREG;   // 60 k-values in LDS

    const int tid  = threadIdx.x;
    const int team = tid / 320;
    const int tj   = tid % 320;        // row index within team (0..319)
    const int bb   = blockIdx.x * 2 + team;   // batch element (BT=1)
    const int g    = tj / 100;
    const int i    = tj % 100;

    __shared__ __align__(16) float whh_l[(KLDS / 4) * GG * 4];  // 72000 B
    __shared__ __align__(16) float h_s[2][1][HH];
    __shared__ __align__(16) float x_s[2][1][KP];
    __shared__ float r_s[2][HH];
    __shared__ float z_s[2][HH];

    // ---- weight rows into registers (one-time, clamped row for pads) ----
    const int jj = (tj < GG) ? tj : 0;
    float wih[KP];
    ldN(std::make_index_sequence<K>{}, wih, Wih + (long)jj * K);
    #pragma unroll
    for (int k = K; k < KP; ++k) wih[k] = 0.f;
    float whr[KREG];
    ldN(std::make_index_sequence<KREG>{}, whr, Whh + (long)jj * HH);
    float bi = bih[jj];
    float bh = bhh[jj];

    // ---- stage whh k>=KREG into LDS, k-packed ----
    for (int idx = tid; idx < GG * KLDS; idx += 640) {
        int row = idx / KLDS, kk = idx % KLDS;
        whh_l[((kk >> 2) * GG + row) * 4 + (kk & 3)] = Whh[row * HH + KREG + kk];
    }

    // ---- init h (per team) ----
    for (int idx = tj; idx < HH; idx += 320)
        h_s[team][0][idx] = h_init ? h_init[bb * HH + idx] : 0.f;
    // ---- init x_s for t=0 ----
    if (tj < KP) {
        if constexpr (EMB) {
            int t0 = tgt[bb];
            x_s[team][0][tj] = (tj < K) ? emb[t0 * K + tj] : 0.f;
        } else {
            x_s[team][0][tj] = (tj < K) ? xin[bb * K + tj] : 0.f;
        }
    }
    __syncthreads();   // whh_l, h_s, x_s ready

    // ---- time loop ----
    for (int t = 0; t < T; ++t) {
        const bool has_next = (t + 1 < T);

        // prefetch next step's input into regs (hidden under FMA loop)
        float px = 0.f;
        if (has_next && tj < KP) {
            if constexpr (EMB) {
                int ptg = tgt[(t + 1) * TB + bb];
                px = (tj < K) ? emb[ptg * K + tj] : 0.f;
            } else {
                if (tj < K) px = xin[((t + 1) * TB + bb) * K + tj];
            }
        }

        // main GEMV: acc_i = Wih[j,:].x + bi ; acc_h = Whh[j,:].h + bh
        float acc_i[1], acc_h[1];
        acc_i[0] = bi;
        acc_h[0] = bh;

        gemv4<1, KP>(std::make_index_sequence<KP / 4>{}, wih, x_s[team], acc_i);
        // acc_h chain: groups 0..9 from regs, 10..24 from LDS (same order)
        gemv4<1, HH>(std::make_index_sequence<KREG / 4>{}, whr, h_s[team], acc_h);
        gemv_lds<KREG / 4, 1>(std::make_index_sequence<KLDS / 4>{},
                              whh_l, jj, h_s[team], acc_h);

        // r / z gates -> LDS
        if (tj < 200) {
            float v = sigmoidf_(acc_i[0] + acc_h[0]);
            if (g == 0) r_s[team][i] = v;
            else        z_s[team][i] = v;
        }
        __syncthreads();   // B1: gates visible; h_s/x_s reads done

        if (tj >= 200 && tj < 300) {
            // n gate + state update (100 threads per team)
            float n  = tanhf_(acc_i[0] + r_s[team][i] * acc_h[0]);
            float z  = z_s[team][i];
            float hn = (1.f - z) * n + z * h_s[team][0][i];
            h_s[team][0][i] = hn;
            if (WRITE_SEQ)
                seq_out[((long)t * TB + bb) * HH + i] = hn;
        } else if (has_next && tj < KP) {
            x_s[team][0][tj] = px;
        }
        __syncthreads();       // step barrier: h_s and x_s ready
    }

    if (h_last != nullptr && tj >= 200 && tj < 300)
        h_last[bb * HH + i] = h_s[team][0][i];
}

// ===========================================================================
// Big-K GRU (K=100): R10 structure. 640 thr = 2 teams x (300+20), BT=2 per
// team, grid 256. whh k-packed in LDS (120KB -> 1 block/CU), wih[100] in
// regs. Pins removed; plain launch_bounds(640) lets the 10-wave residency
// constraint set the cap (~170) so wih is arch-resident without copy tax.
// ===========================================================================
template<bool WRITE_SEQ>
__global__ __launch_bounds__(640)
void gru_big(const float* __restrict__ xin,   // [T,B,100]
             const float* __restrict__ Wih,   // [300,100]
             const float* __restrict__ Whh,   // [300,100]
             const float* __restrict__ bih,
             const float* __restrict__ bhh,
             const float* __restrict__ h_init,// [B,100] or null -> zeros
             float* __restrict__ seq_out,     // [T,B,100] (if WRITE_SEQ)
             float* __restrict__ h_last,      // [B,100] or null
             int T)
{
    constexpr int K  = 100;
    constexpr int KP = 100;
    constexpr int BT = 2;              // batch per team
    constexpr int NT = 2;              // teams

    const int tid  = threadIdx.x;
    const int team = tid / 320;
    const int tj   = tid % 320;        // row index within team (0..319)
    const int bb0  = blockIdx.x * (BT * NT) + team * BT;
    const int g    = tj / 100;
    const int i    = tj % 100;

    __shared__ __align__(16) float whh_l[(HH / 4) * GG * 4];  // 120000 B
    __shared__ __align__(16) float h_s[NT][BT][HH];
    __shared__ __align__(16) float x_s[NT][BT][KP];
    __shared__ float r_s[NT][BT][HH];
    __shared__ float z_s[NT][BT][HH];

    // ---- wih row into registers (one-time, clamped row for pads) ----
    const int jj = (tj < GG) ? tj : 0;
    float wih[KP];
    ldN(std::make_index_sequence<K>{}, wih, Wih + (long)jj * K);
    float bi = bih[jj];
    float bh = bhh[jj];

    // ---- stage whh into LDS, k-packed: whh_l[(k/4)*GG + row][k%4] ----
    for (int idx = tid; idx < GG * HH; idx += 640) {
        int row = idx / HH, k = idx % HH;
        whh_l[((k >> 2) * GG + row) * 4 + (k & 3)] = Whh[row * HH + k];
    }

    // ---- init h (per team) ----
    for (int idx = tj; idx < BT * HH; idx += 320) {
        int b = idx / HH, k = idx % HH;
        h_s[team][b][k] = h_init ? h_init[(bb0 + b) * HH + k] : 0.f;
    }
    // ---- init x_s for t=0 ----
    for (int idx = tj; idx < BT * KP; idx += 320) {
        int b = idx / KP, k = idx % KP;
        x_s[team][b][k] = xin[(bb0 + b) * K + k];
    }
    __syncthreads();   // whh_l, h_s, x_s ready

    // ---- time loop ----
    for (int t = 0; t < T; ++t) {
        const bool has_next = (t + 1 < T);

        // prefetch next step's input into regs (hidden under FMA loop)
        float px = 0.f;
        if (has_next && !(tj >= 200 && tj < 300)) {
            int stid = (tj < 200) ? tj : tj - 100;   // 0..219
            if (stid < BT * K)
                px = xin[((t + 1) * TB + bb0 + stid / K) * K + stid % K];
        }

        // main GEMV: acc_i = Wih[j,:].x + bi ; acc_h = Whh[j,:].h + bh
        float acc_i[BT], acc_h[BT];
        #pragma unroll
        for (int b = 0; b < BT; ++b) { acc_i[b] = bi; acc_h[b] = bh; }

        gemv4<BT, KP>(std::make_index_sequence<KP / 4>{}, wih, x_s[team], acc_i);
        gemv_lds<0, BT>(std::make_index_sequence<HH / 4>{},
                        whh_l, jj, h_s[team], acc_h);

        // r / z gates -> LDS
        if (tj < 200) {
            #pragma unroll
            for (int b = 0; b < BT; ++b) {
                float v = sigmoidf_(acc_i[b] + acc_h[b]);
                if (g == 0) r_s[team][b][i] = v;
                else        z_s[team][b][i] = v;
            }
        }
        __syncthreads();   // B1: gates visible

        if (tj >= 200 && tj < 300) {
            // n gate + state update (100 threads per team)
            #pragma unroll
            for (int b = 0; b < BT; ++b) {
                float n  = tanhf_(acc_i[b] + r_s[team][b][i] * acc_h[b]);
                float z  = z_s[team][b][i];
                float hn = (1.f - z) * n + z * h_s[team][b][i];
                h_s[team][b][i] = hn;
                if (WRITE_SEQ)
                    seq_out[((long)t * TB + bb0 + b) * HH + i] = hn;
            }
        } else {
            if (has_next) {
                int stid = (tj < 200) ? tj : tj - 100;
                if (stid < BT * K) x_s[team][stid / K][stid % K] = px;
            }
        }
        __syncthreads();       // step barrier: h_s and x_s ready
    }

    if (h_last != nullptr && tj >= 200 && tj < 300) {
        #pragma unroll
        for (int b = 0; b < BT; ++b)
            h_last[(bb0 + b) * HH + i] = h_s[team][b][i];
    }
}

// Final linear + argmax + target_cal.
// block = 256 = 4 slots x 64 lanes (lane = output class d, wave = one (p,b) slot)
__global__ __launch_bounds__(256)
void final_kernel(const float* __restrict__ d1,
                  const float* __restrict__ linW,   // [64,100]
                  const float* __restrict__ linb,   // [64]
                  const int*   __restrict__ tgt,    // [80,1024]
                  float* __restrict__ out0,         // [79*1024,64] logits
                  float* __restrict__ out1,         // [79*1024] target_cal
                  float* __restrict__ out2)         // [79*1024] argmax
{
    __shared__ float WT[HH][64];     // WT[k][d]
    __shared__ __align__(16) float row[4][HH];

    const int tid = threadIdx.x;
    for (int idx = tid; idx < 64 * HH; idx += 256) {
        int d = idx / HH, k = idx % HH;
        WT[k][d] = linW[idx];
    }
    const int s    = tid >> 6;
    const int d    = tid & 63;
    const int slot = blockIdx.x * 4 + s;     // < 79*1024
    const int p    = slot >> 10;
    const int b    = slot & 1023;
    const float* drow = &d1[(long)(p * TB + b) * HH];
    __syncthreads();
    if (d < 50) {
        float2 v = *reinterpret_cast<const float2*>(&drow[2 * d]);
        row[s][2 * d]     = v.x;
        row[s][2 * d + 1] = v.y;
    }
    __syncthreads();

    float acc = linb[d];
    #pragma unroll
    for (int k = 0; k < HH; ++k)
        acc += row[s][k] * WT[k][d];

    out0[(long)slot * 64 + d] = acc;

    // argmax over 64 lanes, first-occurrence tie-break (min index among maxima)
    float mv = acc;
    int   mi = d;
    #pragma unroll
    for (int off = 32; off >= 1; off >>= 1) {
        float ov = __shfl_xor(mv, off, 64);
        int   oi = __shfl_xor(mi, off, 64);
        if (ov > mv || (ov == mv && oi < mi)) { mv = ov; mi = oi; }
    }
    if (d == 0) out2[slot] = (float)mi;
    if (d == 1) out1[slot] = (float)tgt[(p + 1) * TB + b];
}

extern "C" void kernel_launch(void* const* d_in, const int* in_sizes, int n_in,
                              void* d_out, int out_size, void* d_ws, size_t ws_size,
                              hipStream_t stream)
{
    const float* x      = (const float*)d_in[0];
    const int*   target = (const int*)  d_in[1];
    const float* emb    = (const float*)d_in[2];
    const float* eWih0  = (const float*)d_in[3];
    const float* eWhh0  = (const float*)d_in[4];
    const float* ebih0  = (const float*)d_in[5];
    const float* ebhh0  = (const float*)d_in[6];
    const float* eWih1  = (const float*)d_in[7];
    const float* eWhh1  = (const float*)d_in[8];
    const float* ebih1  = (const float*)d_in[9];
    const float* ebhh1  = (const float*)d_in[10];
    const float* dWih0  = (const float*)d_in[11];
    const float* dWhh0  = (const float*)d_in[12];
    const float* dbih0  = (const float*)d_in[13];
    const float* dbhh0  = (const float*)d_in[14];
    const float* dWih1  = (const float*)d_in[15];
    const float* dWhh1  = (const float*)d_in[16];
    const float* dbih1  = (const float*)d_in[17];
    const float* dbhh1  = (const float*)d_in[18];
    const float* linW   = (const float*)d_in[19];
    const float* linb   = (const float*)d_in[20];

    // workspace layout (floats):
    //  [0, 102400)                       h_enc0
    //  [102400, 204800)                  h_enc1
    //  [204800, 204800+51.2M)            e0 during encoder
    //  same region reused for d0/d1 during decoder (e0 dead by then)
    float* ws     = (float*)d_ws;
    float* h_enc0 = ws;
    float* h_enc1 = ws + 102400;
    float* e0     = ws + 204800;                      // 500*1024*100
    float* d0     = ws + 204800;                      // aliases e0 (dead)
    float* d1_    = ws + 204800 + 80 * 1024 * 100;    // 80*1024*100

    // encoder layer 0: raw x input (K=26), write e0 + h_enc0
    gru_small<false, true ><<<dim3(512), dim3(640), 0, stream>>>(
        x, nullptr, nullptr, eWih0, eWhh0, ebih0, ebhh0, nullptr, e0, h_enc0, 500);
    // encoder layer 1: e0 input (K=100), only h_enc1 needed
    gru_big<false><<<dim3(256), dim3(640), 0, stream>>>(
        e0, eWih1, eWhh1, ebih1, ebhh1, nullptr, nullptr, h_enc1, 500);
    // decoder layer 0: embedding-gather input (K=26), h0 = h_enc0
    gru_small<true,  true ><<<dim3(512), dim3(640), 0, stream>>>(
        nullptr, target, emb, dWih0, dWhh0, dbih0, dbhh0, h_enc0, d0, nullptr, 80);
    // decoder layer 1: d0 input (K=100), h0 = h_enc1, write d1
    gru_big<true ><<<dim3(256), dim3(640), 0, stream>>>(
        d0, dWih1, dWhh1, dbih1, dbhh1, h_enc1, d1_, nullptr, 80);

    float* out0 = (float*)d_out;
    float* out1 = out0 + (long)79 * 1024 * 64;
    float* out2 = out1 + 79 * 1024;
    final_kernel<<<dim3(20224), dim3(256), 0, stream>>>(d1_, linW, linb, target,
                                                        out0, out1, out2);
}